// Round 1
// baseline (95.159 us; speedup 1.0000x reference)
//
#include <hip/hip_runtime.h>

// Attention branch of the reference is the constant 1.0 (softmax over a
// size-1 axis). Survivor:
//   out[b, o*576 + p] = 1 + gelu( conv3x3(x4, local_w, groups=2, pad=1)*s[o] + t[o] )
// s[o] = bnc1_gamma[o]*rsqrt(1+eps), t[o] = bnc1_beta[o]; NCHW flat order.
//
// V2 structure (vs V1's 256 blocks x 576 thr, 1 load per FMA, 2.25 waves/SIMD):
//   grid  = 2 * 128 * 9 = 2304 blocks  (b, o, quarter-of-9 spatial chunk of 64 pos)
//   block = 256 thr = 16 quads (4 adjacent outputs each) x 16 channel-chunks (4 ch each)
//   -> 9216 waves total (~6-8/SIMD), float4 x-row loads (3 load instr / 12 FMA),
//      weights as 9 aligned dwordx4 into registers, 4KB LDS cross-chunk reduce.

__global__ __launch_bounds__(256, 6) void fused_conv_gelu(
    const float* __restrict__ x,    // (2,128,24,24) flat
    const float* __restrict__ lw,   // (128,64,3,3) flat
    const float* __restrict__ gam,  // (128,)
    const float* __restrict__ bet,  // (128,)
    float* __restrict__ out)        // (2,576,128) flat == (2,128,24,24) flat
{
    const int bi   = blockIdx.x;        // 0..2303
    const int qblk = bi % 9;            // spatial chunk: positions [qblk*64, qblk*64+64)
    const int rest = bi / 9;
    const int o    = rest & 127;
    const int b    = rest >> 7;
    const int g    = o >> 6;

    const int tid = threadIdx.x;
    const int q   = tid & 15;           // quad index: 4 consecutive positions
    const int cs  = tid >> 4;           // channel chunk: input channels cs*4 .. cs*4+3

    const int pos0 = qblk * 64 + q * 4; // 24 % 4 == 0 -> quad never crosses a row
    const int h    = pos0 / 24;
    const int w0   = pos0 - h * 24;     // in {0,4,8,12,16,20}

    const bool lz   = (w0 == 0);        // left tap of output w0 is out of row
    const bool rz   = (w0 == 20);       // right tap of output w0+3 is out of row
    const int  loff = lz ? 0 : -1;      // clamped (always in-bounds) addresses
    const int  roff = rz ? 3 : 4;

    // ---- weights: 4 channels x 9 taps = 36 contiguous floats, 144B-aligned ----
    const float* __restrict__ wp = lw + o * 576 + cs * 36;
    float wv[36];
#pragma unroll
    for (int k = 0; k < 9; ++k) {
        const float4 t4 = *reinterpret_cast<const float4*>(wp + 4 * k);
        wv[4 * k + 0] = t4.x; wv[4 * k + 1] = t4.y;
        wv[4 * k + 2] = t4.z; wv[4 * k + 3] = t4.w;
    }

    const float* __restrict__ xg = x + ((b * 128 + g * 64) + cs * 4) * 576;

    float acc0 = 0.f, acc1 = 0.f, acc2 = 0.f, acc3 = 0.f;

#pragma unroll
    for (int c = 0; c < 4; ++c) {
        const float* __restrict__ xc = xg + c * 576;
#pragma unroll
        for (int dh = 0; dh < 3; ++dh) {
            const int hh = h + dh - 1;
            if ((unsigned)hh < 24u) {   // uniform-true in interior blocks
                const float* __restrict__ row = xc + hh * 24 + w0; // 16B aligned
                const float4 m4 = *reinterpret_cast<const float4*>(row);
                float x0 = row[loff]; if (lz) x0 = 0.f;
                float x5 = row[roff]; if (rz) x5 = 0.f;
                const float wt0 = wv[c * 9 + dh * 3 + 0];
                const float wt1 = wv[c * 9 + dh * 3 + 1];
                const float wt2 = wv[c * 9 + dh * 3 + 2];
                acc0 = fmaf(x0,   wt0, acc0);
                acc0 = fmaf(m4.x, wt1, acc0);
                acc0 = fmaf(m4.y, wt2, acc0);
                acc1 = fmaf(m4.x, wt0, acc1);
                acc1 = fmaf(m4.y, wt1, acc1);
                acc1 = fmaf(m4.z, wt2, acc1);
                acc2 = fmaf(m4.y, wt0, acc2);
                acc2 = fmaf(m4.z, wt1, acc2);
                acc2 = fmaf(m4.w, wt2, acc2);
                acc3 = fmaf(m4.z, wt0, acc3);
                acc3 = fmaf(m4.w, wt1, acc3);
                acc3 = fmaf(x5,   wt2, acc3);
            }
        }
    }

    // ---- cross-chunk reduction: 16 partials per output position ----
    __shared__ float red[16][68];       // 68-stride: spreads banks on both sides
    *reinterpret_cast<float4*>(&red[cs][q * 4]) =
        make_float4(acc0, acc1, acc2, acc3);   // (cs*68+q*4)*4B is 16B aligned
    __syncthreads();

    if (tid < 64) {
        float s = 0.f;
#pragma unroll
        for (int k = 0; k < 16; ++k) s += red[k][tid];  // 2-way banked: free
        const float scale = gam[o] * rsqrtf(1.0f + 1e-5f);
        const float shift = bet[o];
        const float y  = fmaf(s, scale, shift);
        const float gl = 0.5f * y * (1.0f + erff(y * 0.70710678118654752f));
        out[b * 73728 + o * 576 + qblk * 64 + tid] = 1.0f + gl;
    }
}

extern "C" void kernel_launch(void* const* d_in, const int* in_sizes, int n_in,
                              void* d_out, int out_size, void* d_ws, size_t ws_size,
                              hipStream_t stream) {
    const float* x   = (const float*)d_in[0];   // x
    const float* lw  = (const float*)d_in[9];   // local_w
    const float* gam = (const float*)d_in[10];  // bnc1_gamma
    const float* bet = (const float*)d_in[11];  // bnc1_beta
    float* out = (float*)d_out;

    fused_conv_gelu<<<dim3(2304), dim3(256), 0, stream>>>(x, lw, gam, bet, out);
}

// Round 2
// 92.952 us; speedup vs baseline: 1.0237x; 1.0237x over previous
//
#include <hip/hip_runtime.h>

// Attention branch of the reference is the constant 1.0 (softmax over a
// size-1 axis). Survivor:
//   out[b, o*576 + p] = 1 + gelu( conv3x3(x4, local_w, groups=2, pad=1)*s[o] + t[o] )
// s[o] = bnc1_gamma[o]*rsqrt(1+eps), t[o] = bnc1_beta[o]; NCHW flat order.
//
// V3 = V2 with the register-spill fixed.
// V2's __launch_bounds__(256,6) capped VGPRs at ~85; the persistent 36-reg
// weight array + pipelined float4 loads exceeded that -> scratch spill in the
// hot loop (kernel residual ~16us vs V1's ~6us). (256,4) caps at 128 VGPR:
// organic usage ~70-90 fits spill-free, still ~5-6 waves/SIMD vs V1's 2.25.
//
// Structure: grid = 2*128*9 blocks (b, o, 64-position spatial chunk),
// block = 256 thr = 16 quads (4 adjacent outputs) x 16 channel-chunks (4 ch);
// float4 x-row loads (3 load instr / 12 FMA), weights as 9 aligned dwordx4,
// 4.25KB LDS cross-chunk reduce (conflict-free both sides).

__global__ __launch_bounds__(256, 4) void fused_conv_gelu(
    const float* __restrict__ x,    // (2,128,24,24) flat
    const float* __restrict__ lw,   // (128,64,3,3) flat
    const float* __restrict__ gam,  // (128,)
    const float* __restrict__ bet,  // (128,)
    float* __restrict__ out)        // (2,576,128) flat == (2,128,24,24) flat
{
    const int bi   = blockIdx.x;        // 0..2303
    const int qblk = bi % 9;            // spatial chunk: positions [qblk*64, qblk*64+64)
    const int rest = bi / 9;
    const int o    = rest & 127;
    const int b    = rest >> 7;
    const int g    = o >> 6;

    const int tid = threadIdx.x;
    const int q   = tid & 15;           // quad index: 4 consecutive positions
    const int cs  = tid >> 4;           // channel chunk: input channels cs*4 .. cs*4+3

    const int pos0 = qblk * 64 + q * 4; // 24 % 4 == 0 -> quad never crosses a row
    const int h    = pos0 / 24;
    const int w0   = pos0 - h * 24;     // in {0,4,8,12,16,20}

    const bool lz   = (w0 == 0);        // left tap of output w0 is out of row
    const bool rz   = (w0 == 20);       // right tap of output w0+3 is out of row
    const int  loff = lz ? 0 : -1;      // clamped (always in-bounds) addresses
    const int  roff = rz ? 3 : 4;

    // ---- weights: 4 channels x 9 taps = 36 contiguous floats, 144B-aligned ----
    const float* __restrict__ wp = lw + o * 576 + cs * 36;
    float wv[36];
#pragma unroll
    for (int k = 0; k < 9; ++k) {
        const float4 t4 = *reinterpret_cast<const float4*>(wp + 4 * k);
        wv[4 * k + 0] = t4.x; wv[4 * k + 1] = t4.y;
        wv[4 * k + 2] = t4.z; wv[4 * k + 3] = t4.w;
    }

    const float* __restrict__ xg = x + ((b * 128 + g * 64) + cs * 4) * 576;

    float acc0 = 0.f, acc1 = 0.f, acc2 = 0.f, acc3 = 0.f;

#pragma unroll
    for (int c = 0; c < 4; ++c) {
        const float* __restrict__ xc = xg + c * 576;
#pragma unroll
        for (int dh = 0; dh < 3; ++dh) {
            const int hh = h + dh - 1;
            if ((unsigned)hh < 24u) {   // uniform-true in interior blocks
                const float* __restrict__ row = xc + hh * 24 + w0; // 16B aligned
                const float4 m4 = *reinterpret_cast<const float4*>(row);
                float x0 = row[loff]; if (lz) x0 = 0.f;
                float x5 = row[roff]; if (rz) x5 = 0.f;
                const float wt0 = wv[c * 9 + dh * 3 + 0];
                const float wt1 = wv[c * 9 + dh * 3 + 1];
                const float wt2 = wv[c * 9 + dh * 3 + 2];
                acc0 = fmaf(x0,   wt0, acc0);
                acc0 = fmaf(m4.x, wt1, acc0);
                acc0 = fmaf(m4.y, wt2, acc0);
                acc1 = fmaf(m4.x, wt0, acc1);
                acc1 = fmaf(m4.y, wt1, acc1);
                acc1 = fmaf(m4.z, wt2, acc1);
                acc2 = fmaf(m4.y, wt0, acc2);
                acc2 = fmaf(m4.z, wt1, acc2);
                acc2 = fmaf(m4.w, wt2, acc2);
                acc3 = fmaf(m4.z, wt0, acc3);
                acc3 = fmaf(m4.w, wt1, acc3);
                acc3 = fmaf(x5,   wt2, acc3);
            }
        }
    }

    // ---- cross-chunk reduction: 16 partials per output position ----
    __shared__ float red[16][68];       // 68-stride: conflict-free on both sides
    *reinterpret_cast<float4*>(&red[cs][q * 4]) =
        make_float4(acc0, acc1, acc2, acc3);   // (cs*68+q*4)*4B is 16B aligned
    __syncthreads();

    if (tid < 64) {
        float s = 0.f;
#pragma unroll
        for (int k = 0; k < 16; ++k) s += red[k][tid];  // banks consecutive per k
        const float scale = gam[o] * rsqrtf(1.0f + 1e-5f);
        const float shift = bet[o];
        const float y  = fmaf(s, scale, shift);
        const float gl = 0.5f * y * (1.0f + erff(y * 0.70710678118654752f));
        out[b * 73728 + o * 576 + qblk * 64 + tid] = 1.0f + gl;
    }
}

extern "C" void kernel_launch(void* const* d_in, const int* in_sizes, int n_in,
                              void* d_out, int out_size, void* d_ws, size_t ws_size,
                              hipStream_t stream) {
    const float* x   = (const float*)d_in[0];   // x
    const float* lw  = (const float*)d_in[9];   // local_w
    const float* gam = (const float*)d_in[10];  // bnc1_gamma
    const float* bet = (const float*)d_in[11];  // bnc1_beta
    float* out = (float*)d_out;

    fused_conv_gelu<<<dim3(2304), dim3(256), 0, stream>>>(x, lw, gam, bet, out);
}